// Round 2
// baseline (443.857 us; speedup 1.0000x reference)
//
#include <hip/hip_runtime.h>

#define DIM 1024
#define NQ 6

// One 256-thread block, TWO rows per iteration (grid-stride by 2*gridDim).
// Thread t owns out[d0..d0+3], d0=4t. Weights cached in registers.
//
// Reduction: DPP butterfly (VALU) for xor1/xor2/xor7/xor8, DS shuffles only
// for xor16/xor32. Two independent row-reductions per iteration overlap the
// DS-shuffle + LDS + barrier latency (R1: barrier count halved, ILP doubled).
//   xor1 -> quad_perm[1,0,3,2] (0xB1)
//   xor2 -> quad_perm[2,3,0,1] (0x4E)
//   xor7 -> row_half_mirror    (0x141)
//   xor8 -> row_ror:8          (0x128)
// fold-direction bits s1=(l^(l>>2))&1, s2=(l^(l>>1))&1, s3=(l>>2)&1,
// vperm = 4*s1+2*s2+s3 (bijective on lanes 0..7).
__device__ __forceinline__ float4 add4(float4 a, float4 b) {
    return make_float4(a.x + b.x, a.y + b.y, a.z + b.z, a.w + b.w);
}

template <int CTRL>
__device__ __forceinline__ float dpp_mov(float x) {
    return __int_as_float(__builtin_amdgcn_update_dpp(
        0, __float_as_int(x), CTRL, 0xF, 0xF, true));
}

__device__ __forceinline__ float butterfly6(const float* p, int s1, int s2, int s3) {
    float r4[4];
#pragma unroll
    for (int i = 0; i < 4; ++i) {
        float send = s1 ? p[i] : p[i + 4];
        float keep = s1 ? p[i + 4] : p[i];
        r4[i] = keep + dpp_mov<0xB1>(send);
    }
    float r2[2];
#pragma unroll
    for (int i = 0; i < 2; ++i) {
        float send = s2 ? r4[i] : r4[i + 2];
        float keep = s2 ? r4[i + 2] : r4[i];
        r2[i] = keep + dpp_mov<0x4E>(send);
    }
    float send = s3 ? r2[0] : r2[1];
    float keep = s3 ? r2[1] : r2[0];
    float r1 = keep + dpp_mov<0x141>(send);
    r1 += dpp_mov<0x128>(r1);       // xor8 via row_ror:8 (vperm invariant mod 16)
    r1 += __shfl_xor(r1, 16, 64);   // DS swizzle
    r1 += __shfl_xor(r1, 32, 64);   // DS permute
    return r1;
}

__global__ __launch_bounds__(256, 4) void ffq_fused(
    const float* __restrict__ x,
    const float* __restrict__ w1,
    const float* __restrict__ b1,
    const float* __restrict__ theta,
    const float* __restrict__ w2,
    const float* __restrict__ b2,
    float* __restrict__ out,
    int n_rows)
{
    const int t    = threadIdx.x;
    const int lane = t & 63;
    const int wave = t >> 6;
    const int d0   = t * 4;

    // ---- register-cached weights (reused across all rows) ----
    float w1f[NQ][4];
#pragma unroll
    for (int q = 0; q < NQ; ++q) {
        float4 v = *reinterpret_cast<const float4*>(w1 + q * DIM + d0);
        w1f[q][0] = v.x; w1f[q][1] = v.y; w1f[q][2] = v.z; w1f[q][3] = v.w;
    }
    float w2f[4][NQ];  // w2f[i][q] = w2[(d0+i)*6 + q]
    {
        const float4* wp = reinterpret_cast<const float4*>(w2 + (size_t)d0 * NQ);
        float* flat = &w2f[0][0];
#pragma unroll
        for (int i = 0; i < 6; ++i) {
            float4 v = wp[i];
            flat[4 * i + 0] = v.x; flat[4 * i + 1] = v.y;
            flat[4 * i + 2] = v.z; flat[4 * i + 3] = v.w;
        }
    }
    const float4 b2v = *reinterpret_cast<const float4*>(b2 + d0);
    float b1f[NQ], ctf[NQ];
#pragma unroll
    for (int q = 0; q < NQ; ++q) {
        b1f[q] = b1[q];
        ctf[q] = __cosf(theta[q]);
    }

    const int s1 = (lane ^ (lane >> 2)) & 1;
    const int s2 = (lane ^ (lane >> 1)) & 1;
    const int s3 = (lane >> 2) & 1;
    const int vperm = 4 * s1 + 2 * s2 + s3;

    __shared__ __align__(16) float red[2][2][4][8];  // [parity][rowslot][wave][value]

    const int stride2 = gridDim.x * 2;
    int r = blockIdx.x * 2;
    int par = 0;

    float4 xa = make_float4(0.f, 0.f, 0.f, 0.f);
    float4 xb = make_float4(0.f, 0.f, 0.f, 0.f);
    if (r < n_rows)     xa = *reinterpret_cast<const float4*>(x + (size_t)r * DIM + d0);
    if (r + 1 < n_rows) xb = *reinterpret_cast<const float4*>(x + (size_t)(r + 1) * DIM + d0);

    while (r < n_rows) {
        // prefetch next row pair before the reduction/barrier
        const int rn = r + stride2;
        float4 xan = make_float4(0.f, 0.f, 0.f, 0.f);
        float4 xbn = make_float4(0.f, 0.f, 0.f, 0.f);
        if (rn < n_rows)     xan = *reinterpret_cast<const float4*>(x + (size_t)rn * DIM + d0);
        if (rn + 1 < n_rows) xbn = *reinterpret_cast<const float4*>(x + (size_t)(rn + 1) * DIM + d0);

        // partial dots for both rows
        float pa[8], pb[8];
#pragma unroll
        for (int q = 0; q < NQ; ++q) {
            pa[q] = fmaf(xa.x, w1f[q][0],
                    fmaf(xa.y, w1f[q][1],
                    fmaf(xa.z, w1f[q][2], xa.w * w1f[q][3])));
            pb[q] = fmaf(xb.x, w1f[q][0],
                    fmaf(xb.y, w1f[q][1],
                    fmaf(xb.z, w1f[q][2], xb.w * w1f[q][3])));
        }
        pa[6] = 0.f; pa[7] = 0.f; pb[6] = 0.f; pb[7] = 0.f;

        // two independent butterflies — chains interleave, latency overlaps
        float ra1 = butterfly6(pa, s1, s2, s3);
        float rb1 = butterfly6(pb, s1, s2, s3);

        if (lane < 8) {
            red[par][0][wave][vperm] = ra1;
            red[par][1][wave][vperm] = rb1;
        }
        __syncthreads();

        // combine 4 wave partials per row with b128 broadcast reads, then cos
        const float4* rp = reinterpret_cast<const float4*>(&red[par][0][0][0]);
        float4 alo = add4(add4(rp[0], rp[2]), add4(rp[4], rp[6]));
        float4 ahi = add4(add4(rp[1], rp[3]), add4(rp[5], rp[7]));
        float4 blo = add4(add4(rp[8], rp[10]), add4(rp[12], rp[14]));
        float4 bhi = add4(add4(rp[9], rp[11]), add4(rp[13], rp[15]));

        float qa[NQ], qb[NQ];
        qa[0] = alo.x; qa[1] = alo.y; qa[2] = alo.z; qa[3] = alo.w;
        qa[4] = ahi.x; qa[5] = ahi.y;
        qb[0] = blo.x; qb[1] = blo.y; qb[2] = blo.z; qb[3] = blo.w;
        qb[4] = bhi.x; qb[5] = bhi.y;
#pragma unroll
        for (int q = 0; q < NQ; ++q) {
            qa[q] = __cosf(qa[q] + b1f[q]) * ctf[q];
            qb[q] = __cosf(qb[q] + b1f[q]) * ctf[q];
        }

        float4 oa = b2v, ob = b2v;
#pragma unroll
        for (int q = 0; q < NQ; ++q) {
            oa.x = fmaf(qa[q], w2f[0][q], oa.x);
            oa.y = fmaf(qa[q], w2f[1][q], oa.y);
            oa.z = fmaf(qa[q], w2f[2][q], oa.z);
            oa.w = fmaf(qa[q], w2f[3][q], oa.w);
            ob.x = fmaf(qb[q], w2f[0][q], ob.x);
            ob.y = fmaf(qb[q], w2f[1][q], ob.y);
            ob.z = fmaf(qb[q], w2f[2][q], ob.z);
            ob.w = fmaf(qb[q], w2f[3][q], ob.w);
        }
        oa.x = fmaxf(oa.x, 0.f); oa.y = fmaxf(oa.y, 0.f);
        oa.z = fmaxf(oa.z, 0.f); oa.w = fmaxf(oa.w, 0.f);
        ob.x = fmaxf(ob.x, 0.f); ob.y = fmaxf(ob.y, 0.f);
        ob.z = fmaxf(ob.z, 0.f); ob.w = fmaxf(ob.w, 0.f);

        *reinterpret_cast<float4*>(out + (size_t)r * DIM + d0) = oa;
        if (r + 1 < n_rows)
            *reinterpret_cast<float4*>(out + (size_t)(r + 1) * DIM + d0) = ob;

        xa = xan; xb = xbn;
        r = rn;
        par ^= 1;
    }
}

extern "C" void kernel_launch(void* const* d_in, const int* in_sizes, int n_in,
                              void* d_out, int out_size, void* d_ws, size_t ws_size,
                              hipStream_t stream) {
    const float* x     = (const float*)d_in[0];
    const float* w1    = (const float*)d_in[1];
    const float* b1    = (const float*)d_in[2];
    const float* theta = (const float*)d_in[3];
    const float* w2    = (const float*)d_in[4];
    const float* b2    = (const float*)d_in[5];
    float* out = (float*)d_out;

    const int n_rows = in_sizes[0] / DIM;  // B*S = 65536
    const int blocks = 1024;               // 4 blocks/CU resident at <=128 VGPR
    ffq_fused<<<blocks, 256, 0, stream>>>(x, w1, b1, theta, w2, b2, out, n_rows);
}